// Round 14
// baseline (443.121 us; speedup 1.0000x reference)
//
#include <hip/hip_runtime.h>
#include <hip/hip_fp16.h>

#define HID 128
#define NCLUST 4
#define NGRAPH 64
#define NLAYERS 3
#define NBMAX 512     // max 256-node buckets -> n <= 131072
#define SCAP 5120     // fixed per-bucket stage capacity (mean 4092, sigma~64)
#define BIN_CHUNK 8192

typedef _Float16 f16x8 __attribute__((ext_vector_type(8)));
typedef float f32x4 __attribute__((ext_vector_type(4)));

// ---------------- fused elementwise setup -----------------------------------
// pool=0 | cc=0 | bcur bases | x->fp16 | W0^T fp16 | Wh^T fp16
__global__ __launch_bounds__(256) void k_setup(const float* __restrict__ x,
                                               __half* __restrict__ x16, int nxf,
                                               const float* __restrict__ W0,
                                               __half* __restrict__ W0T,
                                               const float* __restrict__ Wh,
                                               __half* __restrict__ WhT,
                                               float* __restrict__ pool,
                                               int* __restrict__ cc,
                                               int* __restrict__ bcur) {
    long i = (long)blockIdx.x * 256 + threadIdx.x;
    const int P = NLAYERS * NGRAPH * HID;          // 24576
    if (i < P) { pool[i] = 0.f; return; }
    i -= P;
    if (i < 12) { cc[i] = 0; return; }
    i -= 12;
    if (i < NBMAX) { bcur[i] = (int)i * SCAP; return; }
    i -= NBMAX;
    long nx4 = nxf / 4;
    if (i < nx4) {
        long idx = i * 4;
        float4 v = *(const float4*)(x + idx);
        __half2* dst = (__half2*)(x16 + idx);
        dst[0] = __floats2half2_rn(v.x, v.y);
        dst[1] = __floats2half2_rn(v.z, v.w);
        return;
    }
    i -= nx4;
    if (i < NCLUST * 128 * 64) {
        int m = (int)(i >> 13);          // /8192
        int rem = (int)(i & 8191);
        int o = rem >> 6, k = rem & 63;
        W0T[i] = __float2half(W0[(size_t)m * 8192 + (size_t)k * 128 + o]);
        return;
    }
    i -= NCLUST * 128 * 64;
    if (i < 2 * NCLUST * 128 * 128) {
        int m = (int)(i >> 14);          // /16384
        int rem = (int)(i & 16383);
        int o = rem >> 7, k = rem & 127;
        WhT[i] = __float2half(Wh[(size_t)m * 16384 + (size_t)k * 128 + o]);
        return;
    }
}

// ---------------- bin edges into 256-node buckets (fixed bases) -------------
__global__ __launch_bounds__(256) void k_bin(const int* __restrict__ ei,
                                             int* __restrict__ bcur,
                                             unsigned int* __restrict__ stage, int E) {
    __shared__ int hcnt[NBMAX];
    __shared__ int hbase[NBMAX];
    int t = threadIdx.x;
    int start = blockIdx.x * BIN_CHUNK;
    int end = min(start + BIN_CHUNK, E);
    for (int b = t; b < NBMAX; b += 256) hcnt[b] = 0;
    __syncthreads();
    for (int i = start + t; i < end; i += 256)
        atomicAdd(&hcnt[ei[E + i] >> 8], 1);
    __syncthreads();
    for (int b = t; b < NBMAX; b += 256) {
        hbase[b] = hcnt[b] ? atomicAdd(&bcur[b], hcnt[b]) : 0;
        hcnt[b] = 0;
    }
    __syncthreads();
    for (int i = start + t; i < end; i += 256) {
        int c = ei[E + i];
        int b = c >> 8;
        int r = atomicAdd(&hcnt[b], 1);
        stage[hbase[b] + r] = ((unsigned int)(c & 255) << 24) | (unsigned int)ei[i];
    }
}

// ---------------- per-bucket CSR-ify; also emits deg/offs/dinv --------------
__global__ __launch_bounds__(256) void k_csrify(const unsigned int* __restrict__ stage,
                                                const int* __restrict__ bcur,
                                                int* __restrict__ esrc,
                                                int* __restrict__ offs,
                                                int* __restrict__ deg,
                                                float* __restrict__ dinv, int n) {
    __shared__ int sh[256];
    __shared__ int lofs[256];
    __shared__ int lsrc[SCAP];
    int b = blockIdx.x, t = threadIdx.x;
    int base = b * SCAP;
    int cnt = bcur[b] - base;
    sh[t] = 0;
    __syncthreads();
    for (int j = t; j < cnt; j += 256)
        atomicAdd(&sh[stage[base + j] >> 24], 1);
    __syncthreads();
    int v0 = sh[t];
    __syncthreads();
    for (int d = 1; d < 256; d <<= 1) {
        int v = (t >= d) ? sh[t - d] : 0;
        __syncthreads();
        sh[t] += v;
        __syncthreads();
    }
    lofs[t] = sh[t] - v0;  // exclusive
    int node = b * 256 + t;
    if (node < n) {
        offs[node] = base + lofs[t];
        deg[node] = v0;
        dinv[node] = rsqrtf((float)(v0 + 1));
    }
    __syncthreads();
    for (int j = t; j < cnt; j += 256) {
        unsigned int e = stage[base + j];
        int r = atomicAdd(&lofs[e >> 24], 1);
        lsrc[r] = (int)(e & 0xFFFFFFu);
    }
    __syncthreads();
    for (int j = t; j < cnt; j += 256) esrc[base + j] = lsrc[j];
}

// ---------------- cluster bucketing (fixed bases c*n, cursor = count) -------
__global__ void k_cfill(const int* __restrict__ cluster, int* __restrict__ ccur,
                        int* __restrict__ clist, int n) {
    __shared__ int lc[NCLUST];
    __shared__ int lbase[NCLUST];
    int tid = threadIdx.x;
    if (tid < NCLUST) lc[tid] = 0;
    __syncthreads();
    int i = blockIdx.x * blockDim.x + tid;
    int c = -1, lpos = 0;
    if (i < n) { c = cluster[i]; lpos = atomicAdd(&lc[c], 1); }
    __syncthreads();
    if (tid < NCLUST) lbase[tid] = lc[tid] ? atomicAdd(&ccur[tid], lc[tid]) : 0;
    __syncthreads();
    if (i < n) clist[(size_t)c * n + lbase[c] + lpos] = i;
}

// ---------------- 64-ch aggregation: pair-gather (2 edges/instr) ------------
// lanes 0-31 fetch edge 2i's full 128 B row (half2/lane), lanes 32-63 edge
// 2i+1; instruction count halves vs one-edge-per-gather; shfl_xor combine.
__global__ __launch_bounds__(256) void k_agg64(const __half* __restrict__ hin,
                                               const int* __restrict__ offs,
                                               const int* __restrict__ deg,
                                               const int* __restrict__ esrc,
                                               const float* __restrict__ dinv,
                                               __half* __restrict__ out, int n) {
    int node = (int)((blockIdx.x * blockDim.x + threadIdx.x) >> 6);
    if (node >= n) return;
    int lane = threadIdx.x & 63;
    int lo = lane & 31, hi = lane >> 5;
    int s = offs[node], e = s + deg[node];
    const __half2* hp = (const __half2*)hin + lo;  // row stride 32 half2
    float a0 = 0.f, a1 = 0.f;
    int j = s;
    for (; j + 15 < e; j += 16) {
        int4 q0 = *(const int4*)(esrc + j);
        int4 q1 = *(const int4*)(esrc + j + 4);
        int4 q2 = *(const int4*)(esrc + j + 8);
        int4 q3 = *(const int4*)(esrc + j + 12);
        int idx[8];
        idx[0] = hi ? q0.y : q0.x; idx[1] = hi ? q0.w : q0.z;
        idx[2] = hi ? q1.y : q1.x; idx[3] = hi ? q1.w : q1.z;
        idx[4] = hi ? q2.y : q2.x; idx[5] = hi ? q2.w : q2.z;
        idx[6] = hi ? q3.y : q3.x; idx[7] = hi ? q3.w : q3.z;
        float w[8];
        __half2 r[8];
#pragma unroll
        for (int p = 0; p < 8; ++p) {
            w[p] = dinv[idx[p]];
            r[p] = hp[(size_t)idx[p] * 32];
        }
#pragma unroll
        for (int p = 0; p < 8; ++p) {
            float2 f = __half22float2(r[p]);
            a0 = fmaf(w[p], f.x, a0);
            a1 = fmaf(w[p], f.y, a1);
        }
    }
    for (; j + 1 < e; j += 2) {
        int2 q = *(const int2*)(esrc + j);
        int idx = hi ? q.y : q.x;
        float w = dinv[idx];
        float2 f = __half22float2(hp[(size_t)idx * 32]);
        a0 = fmaf(w, f.x, a0);
        a1 = fmaf(w, f.y, a1);
    }
    if (j < e) {  // single leftover edge: hi half contributes 0
        int idx = esrc[j];
        float w = hi ? 0.f : dinv[idx];
        float2 f = __half22float2(hp[(size_t)idx * 32]);
        a0 = fmaf(w, f.x, a0);
        a1 = fmaf(w, f.y, a1);
    }
    a0 += __shfl_xor(a0, 32);
    a1 += __shfl_xor(a1, 32);
    float dm = dinv[node];
    float2 vs = __half22float2(hp[(size_t)node * 32]);
    a0 = dm * fmaf(dm, vs.x, a0);
    a1 = dm * fmaf(dm, vs.y, a1);
    if (!hi)
        ((__half2*)out)[(size_t)node * 32 + lo] = __floats2half2_rn(a0, a1);
}

// ---------------- 128-ch aggregation: pair-gather (2 edges/instr) -----------
// lanes 0-31 fetch edge 2i's full 256 B row (uint2=half4/lane), lanes 32-63
// edge 2i+1. E/2 gather instructions instead of E.
__global__ __launch_bounds__(256) void k_agg128(const __half* __restrict__ hin,
                                                const int* __restrict__ offs,
                                                const int* __restrict__ deg,
                                                const int* __restrict__ esrc,
                                                const float* __restrict__ dinv,
                                                __half* __restrict__ out, int n) {
    int node = (int)((blockIdx.x * blockDim.x + threadIdx.x) >> 6);
    if (node >= n) return;
    int lane = threadIdx.x & 63;
    int lo = lane & 31, hi = lane >> 5;
    int s = offs[node], e = s + deg[node];
    const uint2* hp = (const uint2*)hin + lo;  // row stride 32 uint2 (256 B)
    float a0 = 0.f, a1 = 0.f, a2 = 0.f, a3 = 0.f;
    int j = s;
    for (; j + 15 < e; j += 16) {
        int4 q0 = *(const int4*)(esrc + j);
        int4 q1 = *(const int4*)(esrc + j + 4);
        int4 q2 = *(const int4*)(esrc + j + 8);
        int4 q3 = *(const int4*)(esrc + j + 12);
        int idx[8];
        idx[0] = hi ? q0.y : q0.x; idx[1] = hi ? q0.w : q0.z;
        idx[2] = hi ? q1.y : q1.x; idx[3] = hi ? q1.w : q1.z;
        idx[4] = hi ? q2.y : q2.x; idx[5] = hi ? q2.w : q2.z;
        idx[6] = hi ? q3.y : q3.x; idx[7] = hi ? q3.w : q3.z;
        float w[8];
        uint2 r[8];
#pragma unroll
        for (int p = 0; p < 8; ++p) {
            w[p] = dinv[idx[p]];
            r[p] = hp[(size_t)idx[p] * 32];
        }
#pragma unroll
        for (int p = 0; p < 8; ++p) {
            float2 f01 = __half22float2(*(__half2*)&r[p].x);
            float2 f23 = __half22float2(*(__half2*)&r[p].y);
            a0 = fmaf(w[p], f01.x, a0);
            a1 = fmaf(w[p], f01.y, a1);
            a2 = fmaf(w[p], f23.x, a2);
            a3 = fmaf(w[p], f23.y, a3);
        }
    }
    for (; j + 1 < e; j += 2) {
        int2 q = *(const int2*)(esrc + j);
        int idx = hi ? q.y : q.x;
        float w = dinv[idx];
        uint2 r = hp[(size_t)idx * 32];
        float2 f01 = __half22float2(*(__half2*)&r.x);
        float2 f23 = __half22float2(*(__half2*)&r.y);
        a0 = fmaf(w, f01.x, a0);
        a1 = fmaf(w, f01.y, a1);
        a2 = fmaf(w, f23.x, a2);
        a3 = fmaf(w, f23.y, a3);
    }
    if (j < e) {  // single leftover edge: hi half contributes 0
        int idx = esrc[j];
        float w = hi ? 0.f : dinv[idx];
        uint2 r = hp[(size_t)idx * 32];
        float2 f01 = __half22float2(*(__half2*)&r.x);
        float2 f23 = __half22float2(*(__half2*)&r.y);
        a0 = fmaf(w, f01.x, a0);
        a1 = fmaf(w, f01.y, a1);
        a2 = fmaf(w, f23.x, a2);
        a3 = fmaf(w, f23.y, a3);
    }
    a0 += __shfl_xor(a0, 32);
    a1 += __shfl_xor(a1, 32);
    a2 += __shfl_xor(a2, 32);
    a3 += __shfl_xor(a3, 32);
    float dm = dinv[node];
    uint2 rs = hp[(size_t)node * 32];
    float2 s01 = __half22float2(*(__half2*)&rs.x);
    float2 s23 = __half22float2(*(__half2*)&rs.y);
    a0 = dm * fmaf(dm, s01.x, a0);
    a1 = dm * fmaf(dm, s01.y, a1);
    a2 = dm * fmaf(dm, s23.x, a2);
    a3 = dm * fmaf(dm, s23.y, a3);
    if (!hi) {
        uint2 o;
        *(__half2*)&o.x = __floats2half2_rn(a0, a1);
        *(__half2*)&o.y = __floats2half2_rn(a2, a3);
        ((uint2*)out)[(size_t)node * 32 + lo] = o;
    }
}

// ---------------- MFMA transform + fused pooling ----------------------------
template <int K>
__global__ __launch_bounds__(256) void k_tf(const __half* __restrict__ agg16,
                                            const __half* __restrict__ WT,
                                            const float* __restrict__ ball,
                                            const int* __restrict__ ccur,
                                            const int* __restrict__ clist,
                                            const int* __restrict__ batch,
                                            float* __restrict__ pool,
                                            __half* __restrict__ hout, int n) {
    __shared__ int idxs[64];
    __shared__ int gb[64];
    __shared__ __half ot[64][136];  // 272 B rows: 16B-aligned
    int c = blockIdx.y;
    int cnt = ccur[c];
    int m0 = blockIdx.x * 64;
    if (m0 >= cnt) return;
    size_t base = (size_t)c * n;
    int tid = threadIdx.x;
    if (tid < 64) {
        int mm = m0 + tid;
        int id = (mm < cnt) ? clist[base + mm] : -1;
        idxs[tid] = id;
        gb[tid] = (id >= 0) ? batch[id] : -1;
    }
    __syncthreads();
    int w = tid >> 6, l = tid & 63;
    int lr = l & 15, lg = l >> 4;
    int arow = idxs[w * 16 + lr];
    int arow_s = arow < 0 ? 0 : arow;
    const __half* Ap = agg16 + (size_t)arow_s * K + lg * 8;
    const __half* Bp = WT + (size_t)c * 128 * K + (size_t)lr * K + lg * 8;
    f32x4 acc[8];
#pragma unroll
    for (int ct = 0; ct < 8; ++ct) acc[ct] = (f32x4){0.f, 0.f, 0.f, 0.f};
#pragma unroll
    for (int k0 = 0; k0 < K; k0 += 32) {
        f16x8 a = *(const f16x8*)(Ap + k0);
#pragma unroll
        for (int ct = 0; ct < 8; ++ct) {
            f16x8 b = *(const f16x8*)(Bp + (size_t)ct * 16 * K + k0);
            acc[ct] = __builtin_amdgcn_mfma_f32_16x16x32_f16(a, b, acc[ct], 0, 0, 0);
        }
    }
#pragma unroll
    for (int ct = 0; ct < 8; ++ct) {
        float bz = ball[c * 128 + ct * 16 + lr];
#pragma unroll
        for (int r = 0; r < 4; ++r) {
            int nl = w * 16 + lg * 4 + r;
            ot[nl][ct * 16 + lr] = __float2half(acc[ct][r] + bz);
        }
    }
    __syncthreads();
    for (int idx = tid; idx < 64 * 16; idx += 256) {
        int nl = idx >> 4, seg = idx & 15;
        int node = idxs[nl];
        if (node >= 0) {
            float4 v = *(const float4*)&ot[nl][seg * 8];
            *(float4*)(hout + (size_t)node * 128 + seg * 8) = v;
        }
    }
    // fused pooling: channel-per-thread segmented reduce over 64 id-sorted rows
    if (tid < 128) {
        float acc2 = 0.f;
        int cur = -1;
        for (int r = 0; r < 64; ++r) {
            int g = gb[r];
            if (g < 0) break;  // invalid rows are a contiguous tail
            if (g != cur) {
                if (cur >= 0) atomicAdd(&pool[cur * HID + tid], acc2);
                acc2 = 0.f;
                cur = g;
            }
            acc2 += __half2float(ot[r][tid]);
        }
        if (cur >= 0) atomicAdd(&pool[cur * HID + tid], acc2);
    }
}

// ---------------- MLP layer 1 (64 blocks — do NOT single-block this) --------
__global__ __launch_bounds__(128) void k_mlp1(const float* __restrict__ pool,
                                              const float* __restrict__ W1,
                                              const float* __restrict__ b1,
                                              float* __restrict__ z1) {
    int g = blockIdx.x, j = threadIdx.x;
    float acc = b1[j];
#pragma unroll 8
    for (int k = 0; k < NLAYERS * HID; ++k) {
        int t = k >> 7, jj = k & 127;
        float a = pool[((size_t)t * NGRAPH + g) * HID + jj];
        acc += a * W1[(size_t)k * HID + j];
    }
    z1[g * HID + j] = acc;
}

// ---------------- BN + ReLU + MLP layer 2 (single block) --------------------
__global__ __launch_bounds__(256) void k_mlp2(const float* __restrict__ z1,
                                              const float* __restrict__ gamma,
                                              const float* __restrict__ beta,
                                              const float* __restrict__ W2,
                                              const float* __restrict__ b2,
                                              float* __restrict__ out) {
    __shared__ float Z[NGRAPH * HID];
    __shared__ float Zn[NGRAPH * HID];
    for (int idx = threadIdx.x; idx < NGRAPH * HID; idx += 256) Z[idx] = z1[idx];
    __syncthreads();
    if (threadIdx.x < HID) {
        int j = threadIdx.x;
        float mu = 0.f;
        for (int g = 0; g < NGRAPH; ++g) mu += Z[g * HID + j];
        mu *= (1.f / NGRAPH);
        float var = 0.f;
        for (int g = 0; g < NGRAPH; ++g) {
            float d = Z[g * HID + j] - mu;
            var += d * d;
        }
        var *= (1.f / NGRAPH);
        float inv = rsqrtf(var + 1e-5f) * gamma[j];
        float bb = beta[j];
        for (int g = 0; g < NGRAPH; ++g) {
            float v = (Z[g * HID + j] - mu) * inv + bb;
            Zn[g * HID + j] = v > 0.f ? v : 0.f;
        }
    }
    __syncthreads();
    for (int idx = threadIdx.x; idx < NGRAPH * 16; idx += 256) {
        int g = idx >> 4, o = idx & 15;
        float acc = b2[o];
#pragma unroll 16
        for (int j = 0; j < HID; ++j) acc += Zn[g * HID + j] * W2[j * 16 + o];
        out[idx] = acc;
    }
}

extern "C" void kernel_launch(void* const* d_in, const int* in_sizes, int n_in,
                              void* d_out, int out_size, void* d_ws, size_t ws_size,
                              hipStream_t stream) {
    const float* x       = (const float*)d_in[0];
    const int*   cluster = (const int*)d_in[1];
    const int*   ei      = (const int*)d_in[2];
    const int*   batch   = (const int*)d_in[3];
    const float* W0      = (const float*)d_in[4];
    const float* b0      = (const float*)d_in[5];
    const float* Wh      = (const float*)d_in[6];
    const float* bh      = (const float*)d_in[7];
    const float* W1      = (const float*)d_in[8];
    const float* b1      = (const float*)d_in[9];
    const float* gamma   = (const float*)d_in[10];
    const float* beta    = (const float*)d_in[11];
    const float* W2      = (const float*)d_in[12];
    const float* b2      = (const float*)d_in[13];

    const int n  = in_sizes[1];
    const int E  = in_sizes[2] / 2;
    const int IN = in_sizes[0] / n;  // 64
    float* out = (float*)d_out;

    const int nbuck = (n + 255) / 256;

    char* ws = (char*)d_ws;
    size_t off = 0;
    auto alloc = [&](size_t b) { size_t o = off; off += (b + 255) & ~(size_t)255; return o; };
    int*    deg    = (int*)(ws + alloc((size_t)n * 4));
    int*    offs   = (int*)(ws + alloc((size_t)n * 4));
    float*  dinv   = (float*)(ws + alloc((size_t)n * 4));
    int*    esrc   = (int*)(ws + alloc((size_t)nbuck * SCAP * 4));
    unsigned int* stage = (unsigned int*)(ws + alloc((size_t)nbuck * SCAP * 4));
    int*    bcur   = (int*)(ws + alloc((size_t)NBMAX * 4));
    int*    cc     = (int*)(ws + alloc(12 * 4));
    int*    clist  = (int*)(ws + alloc((size_t)NCLUST * n * 4));
    __half* x16    = (__half*)(ws + alloc((size_t)n * IN * 2));
    __half* agg16  = (__half*)(ws + alloc((size_t)n * HID * 2));
    __half* hbuf   = (__half*)(ws + alloc((size_t)n * HID * 2));
    __half* W0T    = (__half*)(ws + alloc((size_t)NCLUST * 128 * 64 * 2));
    __half* WhT    = (__half*)(ws + alloc((size_t)2 * NCLUST * 128 * 128 * 2));
    float*  pool   = (float*)(ws + alloc((size_t)NLAYERS * NGRAPH * HID * 4));
    float*  z1     = (float*)(ws + alloc((size_t)NGRAPH * HID * 4));
    int* ccur = cc + 8;

    // setup: pool + cc + bcur + cvt + W transposes, one kernel
    long setup_items = (long)NLAYERS * NGRAPH * HID + 12 + NBMAX +
                       (long)n * IN / 4 + NCLUST * 128 * 64 + 2 * NCLUST * 128 * 128;
    int setup_blocks = (int)((setup_items + 255) / 256);
    hipLaunchKernelGGL(k_setup, dim3(setup_blocks), dim3(256), 0, stream,
                       x, x16, n * IN, W0, W0T, Wh, WhT, pool, cc, bcur);
    hipLaunchKernelGGL(k_bin, dim3((E + BIN_CHUNK - 1) / BIN_CHUNK), dim3(256), 0, stream,
                       ei, bcur, stage, E);
    hipLaunchKernelGGL(k_csrify, dim3(nbuck), dim3(256), 0, stream,
                       stage, bcur, esrc, offs, deg, dinv, n);
    hipLaunchKernelGGL(k_cfill, dim3((n + 255) / 256), dim3(256), 0, stream,
                       cluster, ccur, clist, n);

    dim3 tgrid((n + 63) / 64, NCLUST);
    int aggblocks = (n + 3) / 4;

    // ---- layer 0 (K=64) ----
    hipLaunchKernelGGL(k_agg64, dim3(aggblocks), dim3(256), 0, stream,
                       x16, offs, deg, esrc, dinv, agg16, n);
    hipLaunchKernelGGL(k_tf<64>, tgrid, dim3(256), 0, stream,
                       agg16, W0T, b0, ccur, clist, batch,
                       pool + 0 * NGRAPH * HID, hbuf, n);

    // ---- layers 1..2 (K=128) ----
    for (int t = 1; t < NLAYERS; ++t) {
        hipLaunchKernelGGL(k_agg128, dim3(aggblocks), dim3(256), 0, stream,
                           hbuf, offs, deg, esrc, dinv, agg16, n);
        hipLaunchKernelGGL(k_tf<128>, tgrid, dim3(256), 0, stream,
                           agg16, WhT + (size_t)(t - 1) * NCLUST * 128 * 128,
                           bh + (size_t)(t - 1) * NCLUST * HID,
                           ccur, clist, batch, pool + (size_t)t * NGRAPH * HID, hbuf, n);
    }

    // ---- head ----
    hipLaunchKernelGGL(k_mlp1, dim3(NGRAPH), dim3(128), 0, stream, pool, W1, b1, z1);
    hipLaunchKernelGGL(k_mlp2, dim3(1), dim3(256), 0, stream, z1, gamma, beta, W2, b2, out);

    (void)n_in; (void)out_size; (void)ws_size;
}

// Round 15
// 404.091 us; speedup vs baseline: 1.0966x; 1.0966x over previous
//
#include <hip/hip_runtime.h>
#include <hip/hip_fp16.h>

#define HID 128
#define NCLUST 4
#define NGRAPH 64
#define NLAYERS 3
#define NBMAX 512     // max 256-node buckets -> n <= 131072
#define SCAP 5120     // fixed per-bucket stage capacity (mean 4092, sigma~64)
#define BIN_CHUNK 8192

typedef _Float16 f16x8 __attribute__((ext_vector_type(8)));
typedef float f32x4 __attribute__((ext_vector_type(4)));

// ---------------- fused elementwise setup -----------------------------------
// pool=0 | cc=0 | bcur bases | x->fp16 | W0^T fp16 | Wh^T fp16
__global__ __launch_bounds__(256) void k_setup(const float* __restrict__ x,
                                               __half* __restrict__ x16, int nxf,
                                               const float* __restrict__ W0,
                                               __half* __restrict__ W0T,
                                               const float* __restrict__ Wh,
                                               __half* __restrict__ WhT,
                                               float* __restrict__ pool,
                                               int* __restrict__ cc,
                                               int* __restrict__ bcur) {
    long i = (long)blockIdx.x * 256 + threadIdx.x;
    const int P = NLAYERS * NGRAPH * HID;          // 24576
    if (i < P) { pool[i] = 0.f; return; }
    i -= P;
    if (i < 12) { cc[i] = 0; return; }
    i -= 12;
    if (i < NBMAX) { bcur[i] = (int)i * SCAP; return; }
    i -= NBMAX;
    long nx4 = nxf / 4;
    if (i < nx4) {
        long idx = i * 4;
        float4 v = *(const float4*)(x + idx);
        __half2* dst = (__half2*)(x16 + idx);
        dst[0] = __floats2half2_rn(v.x, v.y);
        dst[1] = __floats2half2_rn(v.z, v.w);
        return;
    }
    i -= nx4;
    if (i < NCLUST * 128 * 64) {
        int m = (int)(i >> 13);          // /8192
        int rem = (int)(i & 8191);
        int o = rem >> 6, k = rem & 63;
        W0T[i] = __float2half(W0[(size_t)m * 8192 + (size_t)k * 128 + o]);
        return;
    }
    i -= NCLUST * 128 * 64;
    if (i < 2 * NCLUST * 128 * 128) {
        int m = (int)(i >> 14);          // /16384
        int rem = (int)(i & 16383);
        int o = rem >> 7, k = rem & 127;
        WhT[i] = __float2half(Wh[(size_t)m * 16384 + (size_t)k * 128 + o]);
        return;
    }
}

// ---------------- bin edges into 256-node buckets (fixed bases) -------------
__global__ __launch_bounds__(256) void k_bin(const int* __restrict__ ei,
                                             int* __restrict__ bcur,
                                             unsigned int* __restrict__ stage, int E) {
    __shared__ int hcnt[NBMAX];
    __shared__ int hbase[NBMAX];
    int t = threadIdx.x;
    int start = blockIdx.x * BIN_CHUNK;
    int end = min(start + BIN_CHUNK, E);
    for (int b = t; b < NBMAX; b += 256) hcnt[b] = 0;
    __syncthreads();
    for (int i = start + t; i < end; i += 256)
        atomicAdd(&hcnt[ei[E + i] >> 8], 1);
    __syncthreads();
    for (int b = t; b < NBMAX; b += 256) {
        hbase[b] = hcnt[b] ? atomicAdd(&bcur[b], hcnt[b]) : 0;
        hcnt[b] = 0;
    }
    __syncthreads();
    for (int i = start + t; i < end; i += 256) {
        int c = ei[E + i];
        int b = c >> 8;
        int r = atomicAdd(&hcnt[b], 1);
        stage[hbase[b] + r] = ((unsigned int)(c & 255) << 24) | (unsigned int)ei[i];
    }
}

// ---------------- per-bucket CSR-ify; emits deg/offs/dinv + cluster lists ---
__global__ __launch_bounds__(256) void k_csrify(const unsigned int* __restrict__ stage,
                                                const int* __restrict__ bcur,
                                                int* __restrict__ esrc,
                                                int* __restrict__ offs,
                                                int* __restrict__ deg,
                                                float* __restrict__ dinv,
                                                const int* __restrict__ cluster,
                                                int* __restrict__ ccur,
                                                int* __restrict__ clist, int n) {
    __shared__ int sh[256];
    __shared__ int lofs[256];
    __shared__ int lsrc[SCAP];
    __shared__ int lcc[NCLUST];
    __shared__ int lcb[NCLUST];
    int b = blockIdx.x, t = threadIdx.x;
    int base = b * SCAP;
    int cnt = bcur[b] - base;
    int node = b * 256 + t;
    sh[t] = 0;
    if (t < NCLUST) lcc[t] = 0;
    __syncthreads();
    for (int j = t; j < cnt; j += 256)
        atomicAdd(&sh[stage[base + j] >> 24], 1);
    // fused cluster bucketing (independent of sh atomics above)
    int c = -1, lp = 0;
    if (node < n) { c = cluster[node]; lp = atomicAdd(&lcc[c], 1); }
    __syncthreads();
    int v0 = sh[t];
    if (t < NCLUST) lcb[t] = lcc[t] ? atomicAdd(&ccur[t], lcc[t]) : 0;
    __syncthreads();
    for (int d = 1; d < 256; d <<= 1) {
        int v = (t >= d) ? sh[t - d] : 0;
        __syncthreads();
        sh[t] += v;
        __syncthreads();
    }
    lofs[t] = sh[t] - v0;  // exclusive
    if (node < n) {
        offs[node] = base + lofs[t];
        deg[node] = v0;
        dinv[node] = rsqrtf((float)(v0 + 1));
        clist[(size_t)c * n + lcb[c] + lp] = node;
    }
    __syncthreads();
    for (int j = t; j < cnt; j += 256) {
        unsigned int e = stage[base + j];
        int r = atomicAdd(&lofs[e >> 24], 1);
        lsrc[r] = (int)(e & 0xFFFFFFu);
    }
    __syncthreads();
    for (int j = t; j < cnt; j += 256) esrc[base + j] = lsrc[j];
}

// ---------------- 64-ch aggregation (one 128 B row per wave-gather) ---------
__global__ __launch_bounds__(256) void k_agg64(const __half* __restrict__ hin,
                                               const int* __restrict__ offs,
                                               const int* __restrict__ deg,
                                               const int* __restrict__ esrc,
                                               const float* __restrict__ dinv,
                                               __half* __restrict__ out, int n) {
    int node = (int)((blockIdx.x * blockDim.x + threadIdx.x) >> 6);
    int lane = threadIdx.x & 63;
    if (node >= n) return;
    int s = offs[node], e = s + deg[node];
    const __half* hp = hin + lane;
    float a0 = 0.f;
    int j = s;
    int lim4 = s + ((e - s) & ~3);
    for (; j < lim4; j += 4) {
        int4 s4 = *(const int4*)(esrc + j);
        float d0 = dinv[s4.x];
        float d1 = dinv[s4.y];
        float d2 = dinv[s4.z];
        float d3 = dinv[s4.w];
        float v0 = __half2float(hp[(size_t)s4.x * 64]);
        float v1 = __half2float(hp[(size_t)s4.y * 64]);
        float v2 = __half2float(hp[(size_t)s4.z * 64]);
        float v3 = __half2float(hp[(size_t)s4.w * 64]);
        a0 = fmaf(d0, v0, a0);
        a0 = fmaf(d1, v1, a0);
        a0 = fmaf(d2, v2, a0);
        a0 = fmaf(d3, v3, a0);
    }
    for (; j < e; ++j) {
        int src = esrc[j];
        a0 = fmaf(dinv[src], __half2float(hp[(size_t)src * 64]), a0);
    }
    float dm = dinv[node];
    a0 = dm * fmaf(dm, __half2float(hp[(size_t)node * 64]), a0);
    out[(size_t)node * 64 + lane] = __float2half(a0);
}

// ---------------- 128-ch aggregation: one 256 B row per wave-gather, 8 deep -
// (R13 winner; slicing (R12) and pair-gather (R14) both regressed: memory
//  pipe charges per contiguous address clump — keep 1 row/instr)
__global__ __launch_bounds__(256) void k_agg128(const __half* __restrict__ hin,
                                                const int* __restrict__ offs,
                                                const int* __restrict__ deg,
                                                const int* __restrict__ esrc,
                                                const float* __restrict__ dinv,
                                                __half* __restrict__ out, int n) {
    int node = (int)((blockIdx.x * blockDim.x + threadIdx.x) >> 6);
    int lane = threadIdx.x & 63;
    if (node >= n) return;
    int s = offs[node], e = s + deg[node];
    const __half2* hp = (const __half2*)hin + lane;  // row stride 64 half2
    float a0 = 0.f, a1 = 0.f;
    int j = s;
    for (; j + 7 < e; j += 8) {
        int4 sa = *(const int4*)(esrc + j);
        int4 sb = *(const int4*)(esrc + j + 4);
        float w0 = dinv[sa.x];
        float w1 = dinv[sa.y];
        float w2 = dinv[sa.z];
        float w3 = dinv[sa.w];
        float w4 = dinv[sb.x];
        float w5 = dinv[sb.y];
        float w6 = dinv[sb.z];
        float w7 = dinv[sb.w];
        float2 v0 = __half22float2(hp[(size_t)sa.x * 64]);
        float2 v1 = __half22float2(hp[(size_t)sa.y * 64]);
        float2 v2 = __half22float2(hp[(size_t)sa.z * 64]);
        float2 v3 = __half22float2(hp[(size_t)sa.w * 64]);
        float2 v4 = __half22float2(hp[(size_t)sb.x * 64]);
        float2 v5 = __half22float2(hp[(size_t)sb.y * 64]);
        float2 v6 = __half22float2(hp[(size_t)sb.z * 64]);
        float2 v7 = __half22float2(hp[(size_t)sb.w * 64]);
        a0 = fmaf(w0, v0.x, a0); a1 = fmaf(w0, v0.y, a1);
        a0 = fmaf(w1, v1.x, a0); a1 = fmaf(w1, v1.y, a1);
        a0 = fmaf(w2, v2.x, a0); a1 = fmaf(w2, v2.y, a1);
        a0 = fmaf(w3, v3.x, a0); a1 = fmaf(w3, v3.y, a1);
        a0 = fmaf(w4, v4.x, a0); a1 = fmaf(w4, v4.y, a1);
        a0 = fmaf(w5, v5.x, a0); a1 = fmaf(w5, v5.y, a1);
        a0 = fmaf(w6, v6.x, a0); a1 = fmaf(w6, v6.y, a1);
        a0 = fmaf(w7, v7.x, a0); a1 = fmaf(w7, v7.y, a1);
    }
    if (j + 3 < e) {
        int4 s4 = *(const int4*)(esrc + j);
        float w0 = dinv[s4.x];
        float w1 = dinv[s4.y];
        float w2 = dinv[s4.z];
        float w3 = dinv[s4.w];
        float2 v0 = __half22float2(hp[(size_t)s4.x * 64]);
        float2 v1 = __half22float2(hp[(size_t)s4.y * 64]);
        float2 v2 = __half22float2(hp[(size_t)s4.z * 64]);
        float2 v3 = __half22float2(hp[(size_t)s4.w * 64]);
        a0 = fmaf(w0, v0.x, a0); a1 = fmaf(w0, v0.y, a1);
        a0 = fmaf(w1, v1.x, a0); a1 = fmaf(w1, v1.y, a1);
        a0 = fmaf(w2, v2.x, a0); a1 = fmaf(w2, v2.y, a1);
        a0 = fmaf(w3, v3.x, a0); a1 = fmaf(w3, v3.y, a1);
        j += 4;
    }
    for (; j < e; ++j) {
        int src = esrc[j];
        float w = dinv[src];
        float2 v = __half22float2(hp[(size_t)src * 64]);
        a0 = fmaf(w, v.x, a0); a1 = fmaf(w, v.y, a1);
    }
    float dm = dinv[node];
    float2 vs = __half22float2(hp[(size_t)node * 64]);
    a0 = dm * fmaf(dm, vs.x, a0);
    a1 = dm * fmaf(dm, vs.y, a1);
    ((__half2*)out)[(size_t)node * 64 + lane] = __floats2half2_rn(a0, a1);
}

// ---------------- MFMA transform + fused pooling ----------------------------
template <int K>
__global__ __launch_bounds__(256) void k_tf(const __half* __restrict__ agg16,
                                            const __half* __restrict__ WT,
                                            const float* __restrict__ ball,
                                            const int* __restrict__ ccur,
                                            const int* __restrict__ clist,
                                            const int* __restrict__ batch,
                                            float* __restrict__ pool,
                                            __half* __restrict__ hout, int n) {
    __shared__ int idxs[64];
    __shared__ int gb[64];
    __shared__ __half ot[64][136];  // 272 B rows: 16B-aligned
    int c = blockIdx.y;
    int cnt = ccur[c];
    int m0 = blockIdx.x * 64;
    if (m0 >= cnt) return;
    size_t base = (size_t)c * n;
    int tid = threadIdx.x;
    if (tid < 64) {
        int mm = m0 + tid;
        int id = (mm < cnt) ? clist[base + mm] : -1;
        idxs[tid] = id;
        gb[tid] = (id >= 0) ? batch[id] : -1;
    }
    __syncthreads();
    int w = tid >> 6, l = tid & 63;
    int lr = l & 15, lg = l >> 4;
    int arow = idxs[w * 16 + lr];
    int arow_s = arow < 0 ? 0 : arow;
    const __half* Ap = agg16 + (size_t)arow_s * K + lg * 8;
    const __half* Bp = WT + (size_t)c * 128 * K + (size_t)lr * K + lg * 8;
    f32x4 acc[8];
#pragma unroll
    for (int ct = 0; ct < 8; ++ct) acc[ct] = (f32x4){0.f, 0.f, 0.f, 0.f};
#pragma unroll
    for (int k0 = 0; k0 < K; k0 += 32) {
        f16x8 a = *(const f16x8*)(Ap + k0);
#pragma unroll
        for (int ct = 0; ct < 8; ++ct) {
            f16x8 b = *(const f16x8*)(Bp + (size_t)ct * 16 * K + k0);
            acc[ct] = __builtin_amdgcn_mfma_f32_16x16x32_f16(a, b, acc[ct], 0, 0, 0);
        }
    }
#pragma unroll
    for (int ct = 0; ct < 8; ++ct) {
        float bz = ball[c * 128 + ct * 16 + lr];
#pragma unroll
        for (int r = 0; r < 4; ++r) {
            int nl = w * 16 + lg * 4 + r;
            ot[nl][ct * 16 + lr] = __float2half(acc[ct][r] + bz);
        }
    }
    __syncthreads();
    for (int idx = tid; idx < 64 * 16; idx += 256) {
        int nl = idx >> 4, seg = idx & 15;
        int node = idxs[nl];
        if (node >= 0) {
            float4 v = *(const float4*)&ot[nl][seg * 8];
            *(float4*)(hout + (size_t)node * 128 + seg * 8) = v;
        }
    }
    // fused pooling: channel-per-thread segmented reduce over 64 rows
    if (tid < 128) {
        float acc2 = 0.f;
        int cur = -1;
        for (int r = 0; r < 64; ++r) {
            int g = gb[r];
            if (g < 0) break;  // invalid rows are a contiguous tail
            if (g != cur) {
                if (cur >= 0) atomicAdd(&pool[cur * HID + tid], acc2);
                acc2 = 0.f;
                cur = g;
            }
            acc2 += __half2float(ot[r][tid]);
        }
        if (cur >= 0) atomicAdd(&pool[cur * HID + tid], acc2);
    }
}

// ---------------- MLP layer 1 (64 blocks — do NOT single-block this) --------
__global__ __launch_bounds__(128) void k_mlp1(const float* __restrict__ pool,
                                              const float* __restrict__ W1,
                                              const float* __restrict__ b1,
                                              float* __restrict__ z1) {
    int g = blockIdx.x, j = threadIdx.x;
    float acc = b1[j];
#pragma unroll 8
    for (int k = 0; k < NLAYERS * HID; ++k) {
        int t = k >> 7, jj = k & 127;
        float a = pool[((size_t)t * NGRAPH + g) * HID + jj];
        acc += a * W1[(size_t)k * HID + j];
    }
    z1[g * HID + j] = acc;
}

// ---------------- BN + ReLU + MLP layer 2 (single block) --------------------
__global__ __launch_bounds__(256) void k_mlp2(const float* __restrict__ z1,
                                              const float* __restrict__ gamma,
                                              const float* __restrict__ beta,
                                              const float* __restrict__ W2,
                                              const float* __restrict__ b2,
                                              float* __restrict__ out) {
    __shared__ float Z[NGRAPH * HID];
    __shared__ float Zn[NGRAPH * HID];
    for (int idx = threadIdx.x; idx < NGRAPH * HID; idx += 256) Z[idx] = z1[idx];
    __syncthreads();
    if (threadIdx.x < HID) {
        int j = threadIdx.x;
        float mu = 0.f;
        for (int g = 0; g < NGRAPH; ++g) mu += Z[g * HID + j];
        mu *= (1.f / NGRAPH);
        float var = 0.f;
        for (int g = 0; g < NGRAPH; ++g) {
            float d = Z[g * HID + j] - mu;
            var += d * d;
        }
        var *= (1.f / NGRAPH);
        float inv = rsqrtf(var + 1e-5f) * gamma[j];
        float bb = beta[j];
        for (int g = 0; g < NGRAPH; ++g) {
            float v = (Z[g * HID + j] - mu) * inv + bb;
            Zn[g * HID + j] = v > 0.f ? v : 0.f;
        }
    }
    __syncthreads();
    for (int idx = threadIdx.x; idx < NGRAPH * 16; idx += 256) {
        int g = idx >> 4, o = idx & 15;
        float acc = b2[o];
#pragma unroll 16
        for (int j = 0; j < HID; ++j) acc += Zn[g * HID + j] * W2[j * 16 + o];
        out[idx] = acc;
    }
}

extern "C" void kernel_launch(void* const* d_in, const int* in_sizes, int n_in,
                              void* d_out, int out_size, void* d_ws, size_t ws_size,
                              hipStream_t stream) {
    const float* x       = (const float*)d_in[0];
    const int*   cluster = (const int*)d_in[1];
    const int*   ei      = (const int*)d_in[2];
    const int*   batch   = (const int*)d_in[3];
    const float* W0      = (const float*)d_in[4];
    const float* b0      = (const float*)d_in[5];
    const float* Wh      = (const float*)d_in[6];
    const float* bh      = (const float*)d_in[7];
    const float* W1      = (const float*)d_in[8];
    const float* b1      = (const float*)d_in[9];
    const float* gamma   = (const float*)d_in[10];
    const float* beta    = (const float*)d_in[11];
    const float* W2      = (const float*)d_in[12];
    const float* b2      = (const float*)d_in[13];

    const int n  = in_sizes[1];
    const int E  = in_sizes[2] / 2;
    const int IN = in_sizes[0] / n;  // 64
    float* out = (float*)d_out;

    const int nbuck = (n + 255) / 256;

    char* ws = (char*)d_ws;
    size_t off = 0;
    auto alloc = [&](size_t b) { size_t o = off; off += (b + 255) & ~(size_t)255; return o; };
    int*    deg    = (int*)(ws + alloc((size_t)n * 4));
    int*    offs   = (int*)(ws + alloc((size_t)n * 4));
    float*  dinv   = (float*)(ws + alloc((size_t)n * 4));
    int*    esrc   = (int*)(ws + alloc((size_t)nbuck * SCAP * 4));
    unsigned int* stage = (unsigned int*)(ws + alloc((size_t)nbuck * SCAP * 4));
    int*    bcur   = (int*)(ws + alloc((size_t)NBMAX * 4));
    int*    cc     = (int*)(ws + alloc(12 * 4));
    int*    clist  = (int*)(ws + alloc((size_t)NCLUST * n * 4));
    __half* x16    = (__half*)(ws + alloc((size_t)n * IN * 2));
    __half* agg16  = (__half*)(ws + alloc((size_t)n * HID * 2));
    __half* hbuf   = (__half*)(ws + alloc((size_t)n * HID * 2));
    __half* W0T    = (__half*)(ws + alloc((size_t)NCLUST * 128 * 64 * 2));
    __half* WhT    = (__half*)(ws + alloc((size_t)2 * NCLUST * 128 * 128 * 2));
    float*  pool   = (float*)(ws + alloc((size_t)NLAYERS * NGRAPH * HID * 4));
    float*  z1     = (float*)(ws + alloc((size_t)NGRAPH * HID * 4));
    int* ccur = cc + 8;

    // setup: pool + cc + bcur + cvt + W transposes, one kernel
    long setup_items = (long)NLAYERS * NGRAPH * HID + 12 + NBMAX +
                       (long)n * IN / 4 + NCLUST * 128 * 64 + 2 * NCLUST * 128 * 128;
    int setup_blocks = (int)((setup_items + 255) / 256);
    hipLaunchKernelGGL(k_setup, dim3(setup_blocks), dim3(256), 0, stream,
                       x, x16, n * IN, W0, W0T, Wh, WhT, pool, cc, bcur);
    hipLaunchKernelGGL(k_bin, dim3((E + BIN_CHUNK - 1) / BIN_CHUNK), dim3(256), 0, stream,
                       ei, bcur, stage, E);
    hipLaunchKernelGGL(k_csrify, dim3(nbuck), dim3(256), 0, stream,
                       stage, bcur, esrc, offs, deg, dinv, cluster, ccur, clist, n);

    dim3 tgrid((n + 63) / 64, NCLUST);
    int aggblocks = (n + 3) / 4;

    // ---- layer 0 (K=64) ----
    hipLaunchKernelGGL(k_agg64, dim3(aggblocks), dim3(256), 0, stream,
                       x16, offs, deg, esrc, dinv, agg16, n);
    hipLaunchKernelGGL(k_tf<64>, tgrid, dim3(256), 0, stream,
                       agg16, W0T, b0, ccur, clist, batch,
                       pool + 0 * NGRAPH * HID, hbuf, n);

    // ---- layers 1..2 (K=128) ----
    for (int t = 1; t < NLAYERS; ++t) {
        hipLaunchKernelGGL(k_agg128, dim3(aggblocks), dim3(256), 0, stream,
                           hbuf, offs, deg, esrc, dinv, agg16, n);
        hipLaunchKernelGGL(k_tf<128>, tgrid, dim3(256), 0, stream,
                           agg16, WhT + (size_t)(t - 1) * NCLUST * 128 * 128,
                           bh + (size_t)(t - 1) * NCLUST * HID,
                           ccur, clist, batch, pool + (size_t)t * NGRAPH * HID, hbuf, n);
    }

    // ---- head ----
    hipLaunchKernelGGL(k_mlp1, dim3(NGRAPH), dim3(128), 0, stream, pool, W1, b1, z1);
    hipLaunchKernelGGL(k_mlp2, dim3(1), dim3(256), 0, stream, z1, gamma, beta, W2, b2, out);

    (void)n_in; (void)out_size; (void)ws_size;
}

// Round 16
// 384.084 us; speedup vs baseline: 1.1537x; 1.0521x over previous
//
#include <hip/hip_runtime.h>
#include <hip/hip_fp16.h>

#define HID 128
#define NCLUST 4
#define NGRAPH 64
#define NLAYERS 3
#define NBMAX 512     // max 256-node buckets -> n <= 131072
#define SCAP 5120     // fixed per-bucket stage capacity (mean 4092, sigma~64)
#define BIN_CHUNK 8192

typedef _Float16 f16x8 __attribute__((ext_vector_type(8)));
typedef float f32x4 __attribute__((ext_vector_type(4)));

// ---------------- fused elementwise setup -----------------------------------
// pool=0 | cc=0 | bcur bases | x->fp16 | W0^T fp16 | Wh^T fp16
__global__ __launch_bounds__(256) void k_setup(const float* __restrict__ x,
                                               __half* __restrict__ x16, int nxf,
                                               const float* __restrict__ W0,
                                               __half* __restrict__ W0T,
                                               const float* __restrict__ Wh,
                                               __half* __restrict__ WhT,
                                               float* __restrict__ pool,
                                               int* __restrict__ cc,
                                               int* __restrict__ bcur) {
    long i = (long)blockIdx.x * 256 + threadIdx.x;
    const int P = NLAYERS * NGRAPH * HID;          // 24576
    if (i < P) { pool[i] = 0.f; return; }
    i -= P;
    if (i < 12) { cc[i] = 0; return; }
    i -= 12;
    if (i < NBMAX) { bcur[i] = (int)i * SCAP; return; }
    i -= NBMAX;
    long nx4 = nxf / 4;
    if (i < nx4) {
        long idx = i * 4;
        float4 v = *(const float4*)(x + idx);
        __half2* dst = (__half2*)(x16 + idx);
        dst[0] = __floats2half2_rn(v.x, v.y);
        dst[1] = __floats2half2_rn(v.z, v.w);
        return;
    }
    i -= nx4;
    if (i < NCLUST * 128 * 64) {
        int m = (int)(i >> 13);          // /8192
        int rem = (int)(i & 8191);
        int o = rem >> 6, k = rem & 63;
        W0T[i] = __float2half(W0[(size_t)m * 8192 + (size_t)k * 128 + o]);
        return;
    }
    i -= NCLUST * 128 * 64;
    if (i < 2 * NCLUST * 128 * 128) {
        int m = (int)(i >> 14);          // /16384
        int rem = (int)(i & 16383);
        int o = rem >> 7, k = rem & 127;
        WhT[i] = __float2half(Wh[(size_t)m * 16384 + (size_t)k * 128 + o]);
        return;
    }
}

// ---------------- bin edges into 256-node buckets (fixed bases) -------------
__global__ __launch_bounds__(256) void k_bin(const int* __restrict__ ei,
                                             int* __restrict__ bcur,
                                             unsigned int* __restrict__ stage, int E) {
    __shared__ int hcnt[NBMAX];
    __shared__ int hbase[NBMAX];
    int t = threadIdx.x;
    int start = blockIdx.x * BIN_CHUNK;
    int end = min(start + BIN_CHUNK, E);
    for (int b = t; b < NBMAX; b += 256) hcnt[b] = 0;
    __syncthreads();
    for (int i = start + t; i < end; i += 256)
        atomicAdd(&hcnt[ei[E + i] >> 8], 1);
    __syncthreads();
    for (int b = t; b < NBMAX; b += 256) {
        hbase[b] = hcnt[b] ? atomicAdd(&bcur[b], hcnt[b]) : 0;
        hcnt[b] = 0;
    }
    __syncthreads();
    for (int i = start + t; i < end; i += 256) {
        int c = ei[E + i];
        int b = c >> 8;
        int r = atomicAdd(&hcnt[b], 1);
        stage[hbase[b] + r] = ((unsigned int)(c & 255) << 24) | (unsigned int)ei[i];
    }
}

// ---------------- per-bucket CSR-ify; emits deg/offs/dinv + cluster lists ---
__global__ __launch_bounds__(256) void k_csrify(const unsigned int* __restrict__ stage,
                                                const int* __restrict__ bcur,
                                                int* __restrict__ esrc,
                                                int* __restrict__ offs,
                                                int* __restrict__ deg,
                                                float* __restrict__ dinv,
                                                const int* __restrict__ cluster,
                                                int* __restrict__ ccur,
                                                int* __restrict__ clist, int n) {
    __shared__ int sh[256];
    __shared__ int lofs[256];
    __shared__ int lsrc[SCAP];
    __shared__ int lcc[NCLUST];
    __shared__ int lcb[NCLUST];
    int b = blockIdx.x, t = threadIdx.x;
    int base = b * SCAP;
    int cnt = bcur[b] - base;
    int node = b * 256 + t;
    sh[t] = 0;
    if (t < NCLUST) lcc[t] = 0;
    __syncthreads();
    for (int j = t; j < cnt; j += 256)
        atomicAdd(&sh[stage[base + j] >> 24], 1);
    // fused cluster bucketing (independent of sh atomics above)
    int c = -1, lp = 0;
    if (node < n) { c = cluster[node]; lp = atomicAdd(&lcc[c], 1); }
    __syncthreads();
    int v0 = sh[t];
    if (t < NCLUST) lcb[t] = lcc[t] ? atomicAdd(&ccur[t], lcc[t]) : 0;
    __syncthreads();
    for (int d = 1; d < 256; d <<= 1) {
        int v = (t >= d) ? sh[t - d] : 0;
        __syncthreads();
        sh[t] += v;
        __syncthreads();
    }
    lofs[t] = sh[t] - v0;  // exclusive
    if (node < n) {
        offs[node] = base + lofs[t];
        deg[node] = v0;
        dinv[node] = rsqrtf((float)(v0 + 1));
        clist[(size_t)c * n + lcb[c] + lp] = node;
    }
    __syncthreads();
    for (int j = t; j < cnt; j += 256) {
        unsigned int e = stage[base + j];
        int r = atomicAdd(&lofs[e >> 24], 1);
        lsrc[r] = (int)(e & 0xFFFFFFu);
    }
    __syncthreads();
    for (int j = t; j < cnt; j += 256) esrc[base + j] = lsrc[j];
}

// ---------------- 64-ch aggregation: scalarized, 16 gathers in flight -------
// node is readfirstlane'd -> offs/deg/esrc/dinv take the scalar path; gather
// address = SGPR base + invariant lane offset (no per-gather VALU addr chain)
__global__ __launch_bounds__(256) void k_agg64(const __half* __restrict__ hin,
                                               const int* __restrict__ offs,
                                               const int* __restrict__ deg,
                                               const int* __restrict__ esrc,
                                               const float* __restrict__ dinv,
                                               __half* __restrict__ out, int n) {
    int node = __builtin_amdgcn_readfirstlane(
        (int)((blockIdx.x * blockDim.x + threadIdx.x) >> 6));
    if (node >= n) return;
    int lane = threadIdx.x & 63;
    int s = offs[node], e = s + deg[node];
    const __half* hp = hin + lane;
    float a0 = 0.f;
    int j = s;
    for (; j + 15 < e; j += 16) {
        int idx[16];
        {
            int4 qa = *(const int4*)(esrc + j);
            int4 qb = *(const int4*)(esrc + j + 4);
            int4 qc = *(const int4*)(esrc + j + 8);
            int4 qd = *(const int4*)(esrc + j + 12);
            idx[0] = qa.x; idx[1] = qa.y; idx[2] = qa.z; idx[3] = qa.w;
            idx[4] = qb.x; idx[5] = qb.y; idx[6] = qb.z; idx[7] = qb.w;
            idx[8] = qc.x; idx[9] = qc.y; idx[10] = qc.z; idx[11] = qc.w;
            idx[12] = qd.x; idx[13] = qd.y; idx[14] = qd.z; idx[15] = qd.w;
        }
        float w[16];
        __half r[16];
#pragma unroll
        for (int p = 0; p < 16; ++p) {
            w[p] = dinv[idx[p]];
            r[p] = hp[(size_t)idx[p] * 64];
        }
#pragma unroll
        for (int p = 0; p < 16; ++p) a0 = fmaf(w[p], __half2float(r[p]), a0);
    }
    for (; j + 3 < e; j += 4) {
        int4 s4 = *(const int4*)(esrc + j);
        float w0 = dinv[s4.x];
        float w1 = dinv[s4.y];
        float w2 = dinv[s4.z];
        float w3 = dinv[s4.w];
        float v0 = __half2float(hp[(size_t)s4.x * 64]);
        float v1 = __half2float(hp[(size_t)s4.y * 64]);
        float v2 = __half2float(hp[(size_t)s4.z * 64]);
        float v3 = __half2float(hp[(size_t)s4.w * 64]);
        a0 = fmaf(w0, v0, a0);
        a0 = fmaf(w1, v1, a0);
        a0 = fmaf(w2, v2, a0);
        a0 = fmaf(w3, v3, a0);
    }
    for (; j < e; ++j) {
        int src = esrc[j];
        a0 = fmaf(dinv[src], __half2float(hp[(size_t)src * 64]), a0);
    }
    float dm = dinv[node];
    a0 = dm * fmaf(dm, __half2float(hp[(size_t)node * 64]), a0);
    out[(size_t)node * 64 + lane] = __float2half(a0);
}

// ---------------- 128-ch aggregation: scalarized, 16 gathers in flight ------
// one full 256 B row per wave-gather (R12 slicing / R14 pair-gather both
// regressed: memory pipe charges per contiguous address clump)
__global__ __launch_bounds__(256) void k_agg128(const __half* __restrict__ hin,
                                                const int* __restrict__ offs,
                                                const int* __restrict__ deg,
                                                const int* __restrict__ esrc,
                                                const float* __restrict__ dinv,
                                                __half* __restrict__ out, int n) {
    int node = __builtin_amdgcn_readfirstlane(
        (int)((blockIdx.x * blockDim.x + threadIdx.x) >> 6));
    if (node >= n) return;
    int lane = threadIdx.x & 63;
    int s = offs[node], e = s + deg[node];
    const __half2* hp = (const __half2*)hin + lane;  // row stride 64 half2
    float a0 = 0.f, a1 = 0.f;
    int j = s;
    for (; j + 15 < e; j += 16) {
        int idx[16];
        {
            int4 qa = *(const int4*)(esrc + j);
            int4 qb = *(const int4*)(esrc + j + 4);
            int4 qc = *(const int4*)(esrc + j + 8);
            int4 qd = *(const int4*)(esrc + j + 12);
            idx[0] = qa.x; idx[1] = qa.y; idx[2] = qa.z; idx[3] = qa.w;
            idx[4] = qb.x; idx[5] = qb.y; idx[6] = qb.z; idx[7] = qb.w;
            idx[8] = qc.x; idx[9] = qc.y; idx[10] = qc.z; idx[11] = qc.w;
            idx[12] = qd.x; idx[13] = qd.y; idx[14] = qd.z; idx[15] = qd.w;
        }
        float w[16];
        __half2 r[16];
#pragma unroll
        for (int p = 0; p < 16; ++p) {
            w[p] = dinv[idx[p]];
            r[p] = hp[(size_t)idx[p] * 64];
        }
#pragma unroll
        for (int p = 0; p < 16; ++p) {
            float2 f = __half22float2(r[p]);
            a0 = fmaf(w[p], f.x, a0);
            a1 = fmaf(w[p], f.y, a1);
        }
    }
    for (; j + 3 < e; j += 4) {
        int4 s4 = *(const int4*)(esrc + j);
        float w0 = dinv[s4.x];
        float w1 = dinv[s4.y];
        float w2 = dinv[s4.z];
        float w3 = dinv[s4.w];
        float2 v0 = __half22float2(hp[(size_t)s4.x * 64]);
        float2 v1 = __half22float2(hp[(size_t)s4.y * 64]);
        float2 v2 = __half22float2(hp[(size_t)s4.z * 64]);
        float2 v3 = __half22float2(hp[(size_t)s4.w * 64]);
        a0 = fmaf(w0, v0.x, a0); a1 = fmaf(w0, v0.y, a1);
        a0 = fmaf(w1, v1.x, a0); a1 = fmaf(w1, v1.y, a1);
        a0 = fmaf(w2, v2.x, a0); a1 = fmaf(w2, v2.y, a1);
        a0 = fmaf(w3, v3.x, a0); a1 = fmaf(w3, v3.y, a1);
    }
    for (; j < e; ++j) {
        int src = esrc[j];
        float w = dinv[src];
        float2 v = __half22float2(hp[(size_t)src * 64]);
        a0 = fmaf(w, v.x, a0); a1 = fmaf(w, v.y, a1);
    }
    float dm = dinv[node];
    float2 vs = __half22float2(hp[(size_t)node * 64]);
    a0 = dm * fmaf(dm, vs.x, a0);
    a1 = dm * fmaf(dm, vs.y, a1);
    ((__half2*)out)[(size_t)node * 64 + lane] = __floats2half2_rn(a0, a1);
}

// ---------------- MFMA transform + fused pooling ----------------------------
template <int K>
__global__ __launch_bounds__(256) void k_tf(const __half* __restrict__ agg16,
                                            const __half* __restrict__ WT,
                                            const float* __restrict__ ball,
                                            const int* __restrict__ ccur,
                                            const int* __restrict__ clist,
                                            const int* __restrict__ batch,
                                            float* __restrict__ pool,
                                            __half* __restrict__ hout, int n) {
    __shared__ int idxs[64];
    __shared__ int gb[64];
    __shared__ __half ot[64][136];  // 272 B rows: 16B-aligned
    int c = blockIdx.y;
    int cnt = ccur[c];
    int m0 = blockIdx.x * 64;
    if (m0 >= cnt) return;
    size_t base = (size_t)c * n;
    int tid = threadIdx.x;
    if (tid < 64) {
        int mm = m0 + tid;
        int id = (mm < cnt) ? clist[base + mm] : -1;
        idxs[tid] = id;
        gb[tid] = (id >= 0) ? batch[id] : -1;
    }
    __syncthreads();
    int w = tid >> 6, l = tid & 63;
    int lr = l & 15, lg = l >> 4;
    int arow = idxs[w * 16 + lr];
    int arow_s = arow < 0 ? 0 : arow;
    const __half* Ap = agg16 + (size_t)arow_s * K + lg * 8;
    const __half* Bp = WT + (size_t)c * 128 * K + (size_t)lr * K + lg * 8;
    f32x4 acc[8];
#pragma unroll
    for (int ct = 0; ct < 8; ++ct) acc[ct] = (f32x4){0.f, 0.f, 0.f, 0.f};
#pragma unroll
    for (int k0 = 0; k0 < K; k0 += 32) {
        f16x8 a = *(const f16x8*)(Ap + k0);
#pragma unroll
        for (int ct = 0; ct < 8; ++ct) {
            f16x8 b = *(const f16x8*)(Bp + (size_t)ct * 16 * K + k0);
            acc[ct] = __builtin_amdgcn_mfma_f32_16x16x32_f16(a, b, acc[ct], 0, 0, 0);
        }
    }
#pragma unroll
    for (int ct = 0; ct < 8; ++ct) {
        float bz = ball[c * 128 + ct * 16 + lr];
#pragma unroll
        for (int r = 0; r < 4; ++r) {
            int nl = w * 16 + lg * 4 + r;
            ot[nl][ct * 16 + lr] = __float2half(acc[ct][r] + bz);
        }
    }
    __syncthreads();
    for (int idx = tid; idx < 64 * 16; idx += 256) {
        int nl = idx >> 4, seg = idx & 15;
        int node = idxs[nl];
        if (node >= 0) {
            float4 v = *(const float4*)&ot[nl][seg * 8];
            *(float4*)(hout + (size_t)node * 128 + seg * 8) = v;
        }
    }
    // fused pooling: channel-per-thread segmented reduce over 64 rows
    if (tid < 128) {
        float acc2 = 0.f;
        int cur = -1;
        for (int r = 0; r < 64; ++r) {
            int g = gb[r];
            if (g < 0) break;  // invalid rows are a contiguous tail
            if (g != cur) {
                if (cur >= 0) atomicAdd(&pool[cur * HID + tid], acc2);
                acc2 = 0.f;
                cur = g;
            }
            acc2 += __half2float(ot[r][tid]);
        }
        if (cur >= 0) atomicAdd(&pool[cur * HID + tid], acc2);
    }
}

// ---------------- MLP layer 1 (64 blocks — do NOT single-block this) --------
__global__ __launch_bounds__(128) void k_mlp1(const float* __restrict__ pool,
                                              const float* __restrict__ W1,
                                              const float* __restrict__ b1,
                                              float* __restrict__ z1) {
    int g = blockIdx.x, j = threadIdx.x;
    float acc = b1[j];
#pragma unroll 8
    for (int k = 0; k < NLAYERS * HID; ++k) {
        int t = k >> 7, jj = k & 127;
        float a = pool[((size_t)t * NGRAPH + g) * HID + jj];
        acc += a * W1[(size_t)k * HID + j];
    }
    z1[g * HID + j] = acc;
}

// ---------------- BN + ReLU + MLP layer 2 (single block) --------------------
__global__ __launch_bounds__(256) void k_mlp2(const float* __restrict__ z1,
                                              const float* __restrict__ gamma,
                                              const float* __restrict__ beta,
                                              const float* __restrict__ W2,
                                              const float* __restrict__ b2,
                                              float* __restrict__ out) {
    __shared__ float Z[NGRAPH * HID];
    __shared__ float Zn[NGRAPH * HID];
    for (int idx = threadIdx.x; idx < NGRAPH * HID; idx += 256) Z[idx] = z1[idx];
    __syncthreads();
    if (threadIdx.x < HID) {
        int j = threadIdx.x;
        float mu = 0.f;
        for (int g = 0; g < NGRAPH; ++g) mu += Z[g * HID + j];
        mu *= (1.f / NGRAPH);
        float var = 0.f;
        for (int g = 0; g < NGRAPH; ++g) {
            float d = Z[g * HID + j] - mu;
            var += d * d;
        }
        var *= (1.f / NGRAPH);
        float inv = rsqrtf(var + 1e-5f) * gamma[j];
        float bb = beta[j];
        for (int g = 0; g < NGRAPH; ++g) {
            float v = (Z[g * HID + j] - mu) * inv + bb;
            Zn[g * HID + j] = v > 0.f ? v : 0.f;
        }
    }
    __syncthreads();
    for (int idx = threadIdx.x; idx < NGRAPH * 16; idx += 256) {
        int g = idx >> 4, o = idx & 15;
        float acc = b2[o];
#pragma unroll 16
        for (int j = 0; j < HID; ++j) acc += Zn[g * HID + j] * W2[j * 16 + o];
        out[idx] = acc;
    }
}

extern "C" void kernel_launch(void* const* d_in, const int* in_sizes, int n_in,
                              void* d_out, int out_size, void* d_ws, size_t ws_size,
                              hipStream_t stream) {
    const float* x       = (const float*)d_in[0];
    const int*   cluster = (const int*)d_in[1];
    const int*   ei      = (const int*)d_in[2];
    const int*   batch   = (const int*)d_in[3];
    const float* W0      = (const float*)d_in[4];
    const float* b0      = (const float*)d_in[5];
    const float* Wh      = (const float*)d_in[6];
    const float* bh      = (const float*)d_in[7];
    const float* W1      = (const float*)d_in[8];
    const float* b1      = (const float*)d_in[9];
    const float* gamma   = (const float*)d_in[10];
    const float* beta    = (const float*)d_in[11];
    const float* W2      = (const float*)d_in[12];
    const float* b2      = (const float*)d_in[13];

    const int n  = in_sizes[1];
    const int E  = in_sizes[2] / 2;
    const int IN = in_sizes[0] / n;  // 64
    float* out = (float*)d_out;

    const int nbuck = (n + 255) / 256;

    char* ws = (char*)d_ws;
    size_t off = 0;
    auto alloc = [&](size_t b) { size_t o = off; off += (b + 255) & ~(size_t)255; return o; };
    int*    deg    = (int*)(ws + alloc((size_t)n * 4));
    int*    offs   = (int*)(ws + alloc((size_t)n * 4));
    float*  dinv   = (float*)(ws + alloc((size_t)n * 4));
    int*    esrc   = (int*)(ws + alloc((size_t)nbuck * SCAP * 4));
    unsigned int* stage = (unsigned int*)(ws + alloc((size_t)nbuck * SCAP * 4));
    int*    bcur   = (int*)(ws + alloc((size_t)NBMAX * 4));
    int*    cc     = (int*)(ws + alloc(12 * 4));
    int*    clist  = (int*)(ws + alloc((size_t)NCLUST * n * 4));
    __half* x16    = (__half*)(ws + alloc((size_t)n * IN * 2));
    __half* agg16  = (__half*)(ws + alloc((size_t)n * HID * 2));
    __half* hbuf   = (__half*)(ws + alloc((size_t)n * HID * 2));
    __half* W0T    = (__half*)(ws + alloc((size_t)NCLUST * 128 * 64 * 2));
    __half* WhT    = (__half*)(ws + alloc((size_t)2 * NCLUST * 128 * 128 * 2));
    float*  pool   = (float*)(ws + alloc((size_t)NLAYERS * NGRAPH * HID * 4));
    float*  z1     = (float*)(ws + alloc((size_t)NGRAPH * HID * 4));
    int* ccur = cc + 8;

    // setup: pool + cc + bcur + cvt + W transposes, one kernel
    long setup_items = (long)NLAYERS * NGRAPH * HID + 12 + NBMAX +
                       (long)n * IN / 4 + NCLUST * 128 * 64 + 2 * NCLUST * 128 * 128;
    int setup_blocks = (int)((setup_items + 255) / 256);
    hipLaunchKernelGGL(k_setup, dim3(setup_blocks), dim3(256), 0, stream,
                       x, x16, n * IN, W0, W0T, Wh, WhT, pool, cc, bcur);
    hipLaunchKernelGGL(k_bin, dim3((E + BIN_CHUNK - 1) / BIN_CHUNK), dim3(256), 0, stream,
                       ei, bcur, stage, E);
    hipLaunchKernelGGL(k_csrify, dim3(nbuck), dim3(256), 0, stream,
                       stage, bcur, esrc, offs, deg, dinv, cluster, ccur, clist, n);

    dim3 tgrid((n + 63) / 64, NCLUST);
    int aggblocks = (n + 3) / 4;

    // ---- layer 0 (K=64) ----
    hipLaunchKernelGGL(k_agg64, dim3(aggblocks), dim3(256), 0, stream,
                       x16, offs, deg, esrc, dinv, agg16, n);
    hipLaunchKernelGGL(k_tf<64>, tgrid, dim3(256), 0, stream,
                       agg16, W0T, b0, ccur, clist, batch,
                       pool + 0 * NGRAPH * HID, hbuf, n);

    // ---- layers 1..2 (K=128) ----
    for (int t = 1; t < NLAYERS; ++t) {
        hipLaunchKernelGGL(k_agg128, dim3(aggblocks), dim3(256), 0, stream,
                           hbuf, offs, deg, esrc, dinv, agg16, n);
        hipLaunchKernelGGL(k_tf<128>, tgrid, dim3(256), 0, stream,
                           agg16, WhT + (size_t)(t - 1) * NCLUST * 128 * 128,
                           bh + (size_t)(t - 1) * NCLUST * HID,
                           ccur, clist, batch, pool + (size_t)t * NGRAPH * HID, hbuf, n);
    }

    // ---- head ----
    hipLaunchKernelGGL(k_mlp1, dim3(NGRAPH), dim3(128), 0, stream, pool, W1, b1, z1);
    hipLaunchKernelGGL(k_mlp2, dim3(1), dim3(256), 0, stream, z1, gamma, beta, W2, b2, out);

    (void)n_in; (void)out_size; (void)ws_size;
}

// Round 18
// 378.329 us; speedup vs baseline: 1.1713x; 1.0152x over previous
//
#include <hip/hip_runtime.h>
#include <hip/hip_fp16.h>

#define HID 128
#define NCLUST 4
#define NGRAPH 64
#define NLAYERS 3
#define NBMAX 512     // max 256-node buckets -> n <= 131072
#define SCAP 5120     // fixed per-bucket stage capacity (mean 4092, sigma~64)
#define BIN_CHUNK 2048

typedef _Float16 f16x8 __attribute__((ext_vector_type(8)));
typedef float f32x4 __attribute__((ext_vector_type(4)));

// ---------------- fused elementwise setup -----------------------------------
// pool=0 | cc=0 | bcur bases | x->fp16 | W0^T fp16 | Wh^T fp16
__global__ __launch_bounds__(256) void k_setup(const float* __restrict__ x,
                                               __half* __restrict__ x16, int nxf,
                                               const float* __restrict__ W0,
                                               __half* __restrict__ W0T,
                                               const float* __restrict__ Wh,
                                               __half* __restrict__ WhT,
                                               float* __restrict__ pool,
                                               int* __restrict__ cc,
                                               int* __restrict__ bcur) {
    long i = (long)blockIdx.x * 256 + threadIdx.x;
    const int P = NLAYERS * NGRAPH * HID;          // 24576
    if (i < P) { pool[i] = 0.f; return; }
    i -= P;
    if (i < 12) { cc[i] = 0; return; }
    i -= 12;
    if (i < NBMAX) { bcur[i] = (int)i * SCAP; return; }
    i -= NBMAX;
    long nx4 = nxf / 4;
    if (i < nx4) {
        long idx = i * 4;
        float4 v = *(const float4*)(x + idx);
        __half2* dst = (__half2*)(x16 + idx);
        dst[0] = __floats2half2_rn(v.x, v.y);
        dst[1] = __floats2half2_rn(v.z, v.w);
        return;
    }
    i -= nx4;
    if (i < NCLUST * 128 * 64) {
        int m = (int)(i >> 13);          // /8192
        int rem = (int)(i & 8191);
        int o = rem >> 6, k = rem & 63;
        W0T[i] = __float2half(W0[(size_t)m * 8192 + (size_t)k * 128 + o]);
        return;
    }
    i -= NCLUST * 128 * 64;
    if (i < 2 * NCLUST * 128 * 128) {
        int m = (int)(i >> 14);          // /16384
        int rem = (int)(i & 16383);
        int o = rem >> 7, k = rem & 127;
        WhT[i] = __float2half(Wh[(size_t)m * 16384 + (size_t)k * 128 + o]);
        return;
    }
}

// ---------------- bin edges into 256-node buckets (fixed bases) -------------
// 2048-edge chunks (782 blocks ~ 3/CU, was 196 = grid-starved); bucket ids
// cached in LDS so the placement pass re-reads nothing from global.
__global__ __launch_bounds__(256) void k_bin(const int* __restrict__ ei,
                                             int* __restrict__ bcur,
                                             unsigned int* __restrict__ stage, int E) {
    __shared__ int hcnt[NBMAX];
    __shared__ int hbase[NBMAX];
    __shared__ unsigned short lb[BIN_CHUNK];
    __shared__ unsigned char llo[BIN_CHUNK];
    int t = threadIdx.x;
    int start = blockIdx.x * BIN_CHUNK;
    int end = min(start + BIN_CHUNK, E);
    int m = end - start;
    for (int b = t; b < NBMAX; b += 256) hcnt[b] = 0;
    __syncthreads();
    for (int i = t; i < m; i += 256) {
        int col = ei[E + start + i];
        lb[i] = (unsigned short)(col >> 8);
        llo[i] = (unsigned char)(col & 255);
        atomicAdd(&hcnt[col >> 8], 1);
    }
    __syncthreads();
    for (int b = t; b < NBMAX; b += 256) {
        hbase[b] = hcnt[b] ? atomicAdd(&bcur[b], hcnt[b]) : 0;
        hcnt[b] = 0;
    }
    __syncthreads();
    for (int i = t; i < m; i += 256) {
        int b = lb[i];
        int r = atomicAdd(&hcnt[b], 1);
        stage[hbase[b] + r] = ((unsigned int)llo[i] << 24) | (unsigned int)ei[start + i];
    }
}

// ---------------- per-bucket CSR-ify (512 thr); emits deg/offs/dinv/clist ---
__global__ __launch_bounds__(512) void k_csrify(const unsigned int* __restrict__ stage,
                                                const int* __restrict__ bcur,
                                                int* __restrict__ esrc,
                                                int* __restrict__ offs,
                                                int* __restrict__ deg,
                                                float* __restrict__ dinv,
                                                const int* __restrict__ cluster,
                                                int* __restrict__ ccur,
                                                int* __restrict__ clist, int n) {
    __shared__ int sh[256];
    __shared__ int lofs[256];
    __shared__ int lsrc[SCAP];
    __shared__ int lcc[NCLUST];
    __shared__ int lcb[NCLUST];
    int b = blockIdx.x, t = threadIdx.x;
    int base = b * SCAP;
    int cnt = bcur[b] - base;
    int node = b * 256 + t;  // valid only for t < 256
    if (t < 256) sh[t] = 0;
    if (t < NCLUST) lcc[t] = 0;
    __syncthreads();
    for (int j = t; j < cnt; j += 512)
        atomicAdd(&sh[stage[base + j] >> 24], 1);
    int c = -1, lp = 0;
    if (t < 256 && node < n) { c = cluster[node]; lp = atomicAdd(&lcc[c], 1); }
    __syncthreads();
    int v0 = (t < 256) ? sh[t] : 0;
    if (t < NCLUST) lcb[t] = lcc[t] ? atomicAdd(&ccur[t], lcc[t]) : 0;
    __syncthreads();
    for (int d = 1; d < 256; d <<= 1) {
        int v = (t >= d && t < 256) ? sh[t - d] : 0;
        __syncthreads();
        if (t < 256) sh[t] += v;
        __syncthreads();
    }
    if (t < 256) lofs[t] = sh[t] - v0;  // exclusive
    if (t < 256 && node < n) {
        offs[node] = base + lofs[t];
        deg[node] = v0;
        dinv[node] = rsqrtf((float)(v0 + 1));
        clist[(size_t)c * n + lcb[c] + lp] = node;
    }
    __syncthreads();
    for (int j = t; j < cnt; j += 512) {
        unsigned int e = stage[base + j];
        int r = atomicAdd(&lofs[e >> 24], 1);
        lsrc[r] = (int)(e & 0xFFFFFFu);
    }
    __syncthreads();
    for (int j = t; j < cnt; j += 512) esrc[base + j] = lsrc[j];
}

// ---------------- 64-ch aggregation: scalarized, 16 gathers in flight -------
__global__ __launch_bounds__(256) void k_agg64(const __half* __restrict__ hin,
                                               const int* __restrict__ offs,
                                               const int* __restrict__ deg,
                                               const int* __restrict__ esrc,
                                               const float* __restrict__ dinv,
                                               __half* __restrict__ out, int n) {
    int node = __builtin_amdgcn_readfirstlane(
        (int)((blockIdx.x * blockDim.x + threadIdx.x) >> 6));
    if (node >= n) return;
    int lane = threadIdx.x & 63;
    int s = offs[node], e = s + deg[node];
    const __half* hp = hin + lane;
    float a0 = 0.f;
    int j = s;
    for (; j + 15 < e; j += 16) {
        int idx[16];
        {
            int4 qa = *(const int4*)(esrc + j);
            int4 qb = *(const int4*)(esrc + j + 4);
            int4 qc = *(const int4*)(esrc + j + 8);
            int4 qd = *(const int4*)(esrc + j + 12);
            idx[0] = qa.x; idx[1] = qa.y; idx[2] = qa.z; idx[3] = qa.w;
            idx[4] = qb.x; idx[5] = qb.y; idx[6] = qb.z; idx[7] = qb.w;
            idx[8] = qc.x; idx[9] = qc.y; idx[10] = qc.z; idx[11] = qc.w;
            idx[12] = qd.x; idx[13] = qd.y; idx[14] = qd.z; idx[15] = qd.w;
        }
        float w[16];
        __half r[16];
#pragma unroll
        for (int p = 0; p < 16; ++p) {
            w[p] = dinv[idx[p]];
            r[p] = hp[(size_t)idx[p] * 64];
        }
#pragma unroll
        for (int p = 0; p < 16; ++p) a0 = fmaf(w[p], __half2float(r[p]), a0);
    }
    for (; j + 3 < e; j += 4) {
        int4 s4 = *(const int4*)(esrc + j);
        float w0 = dinv[s4.x];
        float w1 = dinv[s4.y];
        float w2 = dinv[s4.z];
        float w3 = dinv[s4.w];
        float v0 = __half2float(hp[(size_t)s4.x * 64]);
        float v1 = __half2float(hp[(size_t)s4.y * 64]);
        float v2 = __half2float(hp[(size_t)s4.z * 64]);
        float v3 = __half2float(hp[(size_t)s4.w * 64]);
        a0 = fmaf(w0, v0, a0);
        a0 = fmaf(w1, v1, a0);
        a0 = fmaf(w2, v2, a0);
        a0 = fmaf(w3, v3, a0);
    }
    for (; j < e; ++j) {
        int src = esrc[j];
        a0 = fmaf(dinv[src], __half2float(hp[(size_t)src * 64]), a0);
    }
    float dm = dinv[node];
    a0 = dm * fmaf(dm, __half2float(hp[(size_t)node * 64]), a0);
    out[(size_t)node * 64 + lane] = __float2half(a0);
}

// ---------------- 128-ch aggregation: scalarized, 16 gathers in flight ------
__global__ __launch_bounds__(256) void k_agg128(const __half* __restrict__ hin,
                                                const int* __restrict__ offs,
                                                const int* __restrict__ deg,
                                                const int* __restrict__ esrc,
                                                const float* __restrict__ dinv,
                                                __half* __restrict__ out, int n) {
    int node = __builtin_amdgcn_readfirstlane(
        (int)((blockIdx.x * blockDim.x + threadIdx.x) >> 6));
    if (node >= n) return;
    int lane = threadIdx.x & 63;
    int s = offs[node], e = s + deg[node];
    const __half2* hp = (const __half2*)hin + lane;  // row stride 64 half2
    float a0 = 0.f, a1 = 0.f;
    int j = s;
    for (; j + 15 < e; j += 16) {
        int idx[16];
        {
            int4 qa = *(const int4*)(esrc + j);
            int4 qb = *(const int4*)(esrc + j + 4);
            int4 qc = *(const int4*)(esrc + j + 8);
            int4 qd = *(const int4*)(esrc + j + 12);
            idx[0] = qa.x; idx[1] = qa.y; idx[2] = qa.z; idx[3] = qa.w;
            idx[4] = qb.x; idx[5] = qb.y; idx[6] = qb.z; idx[7] = qb.w;
            idx[8] = qc.x; idx[9] = qc.y; idx[10] = qc.z; idx[11] = qc.w;
            idx[12] = qd.x; idx[13] = qd.y; idx[14] = qd.z; idx[15] = qd.w;
        }
        float w[16];
        __half2 r[16];
#pragma unroll
        for (int p = 0; p < 16; ++p) {
            w[p] = dinv[idx[p]];
            r[p] = hp[(size_t)idx[p] * 64];
        }
#pragma unroll
        for (int p = 0; p < 16; ++p) {
            float2 f = __half22float2(r[p]);
            a0 = fmaf(w[p], f.x, a0);
            a1 = fmaf(w[p], f.y, a1);
        }
    }
    for (; j + 3 < e; j += 4) {
        int4 s4 = *(const int4*)(esrc + j);
        float w0 = dinv[s4.x];
        float w1 = dinv[s4.y];
        float w2 = dinv[s4.z];
        float w3 = dinv[s4.w];
        float2 v0 = __half22float2(hp[(size_t)s4.x * 64]);
        float2 v1 = __half22float2(hp[(size_t)s4.y * 64]);
        float2 v2 = __half22float2(hp[(size_t)s4.z * 64]);
        float2 v3 = __half22float2(hp[(size_t)s4.w * 64]);
        a0 = fmaf(w0, v0.x, a0); a1 = fmaf(w0, v0.y, a1);
        a0 = fmaf(w1, v1.x, a0); a1 = fmaf(w1, v1.y, a1);
        a0 = fmaf(w2, v2.x, a0); a1 = fmaf(w2, v2.y, a1);
        a0 = fmaf(w3, v3.x, a0); a1 = fmaf(w3, v3.y, a1);
    }
    for (; j < e; ++j) {
        int src = esrc[j];
        float w = dinv[src];
        float2 v = __half22float2(hp[(size_t)src * 64]);
        a0 = fmaf(w, v.x, a0); a1 = fmaf(w, v.y, a1);
    }
    float dm = dinv[node];
    float2 vs = __half22float2(hp[(size_t)node * 64]);
    a0 = dm * fmaf(dm, vs.x, a0);
    a1 = dm * fmaf(dm, vs.y, a1);
    ((__half2*)out)[(size_t)node * 64 + lane] = __floats2half2_rn(a0, a1);
}

// ---------------- MFMA transform + fused pooling ----------------------------
// A tile LDS-staged (one full row per wave-gather, agg-style); buf reused as
// output tile after the k-loop (LDS stays 17.4 KB). Stride 136 halves keeps
// ds_read_b128 bank-balanced (272 B rows, 16B-aligned).
template <int K>
__global__ __launch_bounds__(256) void k_tf(const __half* __restrict__ agg16,
                                            const __half* __restrict__ WT,
                                            const float* __restrict__ ball,
                                            const int* __restrict__ ccur,
                                            const int* __restrict__ clist,
                                            const int* __restrict__ batch,
                                            float* __restrict__ pool,
                                            __half* __restrict__ hout, int n) {
    __shared__ int idxs[64];
    __shared__ int gb[64];
    __shared__ __half buf[64][136];
    int c = blockIdx.y;
    int cnt = ccur[c];
    int m0 = blockIdx.x * 64;
    if (m0 >= cnt) return;
    size_t base = (size_t)c * n;
    int tid = threadIdx.x;
    if (tid < 64) {
        int mm = m0 + tid;
        int id = (mm < cnt) ? clist[base + mm] : -1;
        idxs[tid] = id;
        gb[tid] = (id >= 0) ? batch[id] : -1;
    }
    __syncthreads();
    int w = tid >> 6, l = tid & 63;
    // stage A: wave w stages rows w*16..w*16+15, one row-clump per instruction
#pragma unroll
    for (int r = 0; r < 16; ++r) {
        int row = idxs[w * 16 + r];
        int rs = row < 0 ? 0 : row;
        if constexpr (K == 128) {
            __half2 v = ((const __half2*)(agg16 + (size_t)rs * K))[l];
            *((__half2*)&buf[w * 16 + r][0] + l) = v;
        } else {
            buf[w * 16 + r][l] = agg16[(size_t)rs * K + l];
        }
    }
    __syncthreads();
    int lr = l & 15, lg = l >> 4;
    const __half* Bp = WT + (size_t)c * 128 * K + (size_t)lr * K + lg * 8;
    f32x4 acc[8];
#pragma unroll
    for (int ct = 0; ct < 8; ++ct) acc[ct] = (f32x4){0.f, 0.f, 0.f, 0.f};
#pragma unroll
    for (int k0 = 0; k0 < K; k0 += 32) {
        f16x8 a = *(const f16x8*)&buf[w * 16 + lr][lg * 8 + k0];
#pragma unroll
        for (int ct = 0; ct < 8; ++ct) {
            f16x8 b = *(const f16x8*)(Bp + (size_t)ct * 16 * K + k0);
            acc[ct] = __builtin_amdgcn_mfma_f32_16x16x32_f16(a, b, acc[ct], 0, 0, 0);
        }
    }
    __syncthreads();  // A consumed -> reuse buf as output tile
#pragma unroll
    for (int ct = 0; ct < 8; ++ct) {
        float bz = ball[c * 128 + ct * 16 + lr];
#pragma unroll
        for (int r = 0; r < 4; ++r) {
            int nl = w * 16 + lg * 4 + r;
            buf[nl][ct * 16 + lr] = __float2half(acc[ct][r] + bz);
        }
    }
    __syncthreads();
    for (int idx = tid; idx < 64 * 16; idx += 256) {
        int nl = idx >> 4, seg = idx & 15;
        int node = idxs[nl];
        if (node >= 0) {
            float4 v = *(const float4*)&buf[nl][seg * 8];
            *(float4*)(hout + (size_t)node * 128 + seg * 8) = v;
        }
    }
    // fused pooling: channel-per-thread segmented reduce over 64 rows
    if (tid < 128) {
        float acc2 = 0.f;
        int cur = -1;
        for (int r = 0; r < 64; ++r) {
            int g = gb[r];
            if (g < 0) break;  // invalid rows are a contiguous tail
            if (g != cur) {
                if (cur >= 0) atomicAdd(&pool[cur * HID + tid], acc2);
                acc2 = 0.f;
                cur = g;
            }
            acc2 += __half2float(buf[r][tid]);
        }
        if (cur >= 0) atomicAdd(&pool[cur * HID + tid], acc2);
    }
}

// ---------------- MLP layer 1 (64 blocks — do NOT single-block this) --------
__global__ __launch_bounds__(128) void k_mlp1(const float* __restrict__ pool,
                                              const float* __restrict__ W1,
                                              const float* __restrict__ b1,
                                              float* __restrict__ z1) {
    int g = blockIdx.x, j = threadIdx.x;
    float acc = b1[j];
#pragma unroll 8
    for (int k = 0; k < NLAYERS * HID; ++k) {
        int t = k >> 7, jj = k & 127;
        float a = pool[((size_t)t * NGRAPH + g) * HID + jj];
        acc += a * W1[(size_t)k * HID + j];
    }
    z1[g * HID + j] = acc;
}

// ---------------- BN + ReLU + MLP layer 2 (single block) --------------------
__global__ __launch_bounds__(256) void k_mlp2(const float* __restrict__ z1,
                                              const float* __restrict__ gamma,
                                              const float* __restrict__ beta,
                                              const float* __restrict__ W2,
                                              const float* __restrict__ b2,
                                              float* __restrict__ out) {
    __shared__ float Z[NGRAPH * HID];
    __shared__ float Zn[NGRAPH * HID];
    for (int idx = threadIdx.x; idx < NGRAPH * HID; idx += 256) Z[idx] = z1[idx];
    __syncthreads();
    if (threadIdx.x < HID) {
        int j = threadIdx.x;
        float mu = 0.f;
        for (int g = 0; g < NGRAPH; ++g) mu += Z[g * HID + j];
        mu *= (1.f / NGRAPH);
        float var = 0.f;
        for (int g = 0; g < NGRAPH; ++g) {
            float d = Z[g * HID + j] - mu;
            var += d * d;
        }
        var *= (1.f / NGRAPH);
        float inv = rsqrtf(var + 1e-5f) * gamma[j];
        float bb = beta[j];
        for (int g = 0; g < NGRAPH; ++g) {
            float v = (Z[g * HID + j] - mu) * inv + bb;
            Zn[g * HID + j] = v > 0.f ? v : 0.f;
        }
    }
    __syncthreads();
    for (int idx = threadIdx.x; idx < NGRAPH * 16; idx += 256) {
        int g = idx >> 4, o = idx & 15;
        float acc = b2[o];
#pragma unroll 16
        for (int j = 0; j < HID; ++j) acc += Zn[g * HID + j] * W2[j * 16 + o];
        out[idx] = acc;
    }
}

extern "C" void kernel_launch(void* const* d_in, const int* in_sizes, int n_in,
                              void* d_out, int out_size, void* d_ws, size_t ws_size,
                              hipStream_t stream) {
    const float* x       = (const float*)d_in[0];
    const int*   cluster = (const int*)d_in[1];
    const int*   ei      = (const int*)d_in[2];
    const int*   batch   = (const int*)d_in[3];
    const float* W0      = (const float*)d_in[4];
    const float* b0      = (const float*)d_in[5];
    const float* Wh      = (const float*)d_in[6];
    const float* bh      = (const float*)d_in[7];
    const float* W1      = (const float*)d_in[8];
    const float* b1      = (const float*)d_in[9];
    const float* gamma   = (const float*)d_in[10];
    const float* beta    = (const float*)d_in[11];
    const float* W2      = (const float*)d_in[12];
    const float* b2      = (const float*)d_in[13];

    const int n  = in_sizes[1];
    const int E  = in_sizes[2] / 2;
    const int IN = in_sizes[0] / n;  // 64
    float* out = (float*)d_out;

    const int nbuck = (n + 255) / 256;

    char* ws = (char*)d_ws;
    size_t off = 0;
    auto alloc = [&](size_t b) { size_t o = off; off += (b + 255) & ~(size_t)255; return o; };
    int*    deg    = (int*)(ws + alloc((size_t)n * 4));
    int*    offs   = (int*)(ws + alloc((size_t)n * 4));
    float*  dinv   = (float*)(ws + alloc((size_t)n * 4));
    int*    esrc   = (int*)(ws + alloc((size_t)nbuck * SCAP * 4));
    unsigned int* stage = (unsigned int*)(ws + alloc((size_t)nbuck * SCAP * 4));
    int*    bcur   = (int*)(ws + alloc((size_t)NBMAX * 4));
    int*    cc     = (int*)(ws + alloc(12 * 4));
    int*    clist  = (int*)(ws + alloc((size_t)NCLUST * n * 4));
    __half* x16    = (__half*)(ws + alloc((size_t)n * IN * 2));
    __half* agg16  = (__half*)(ws + alloc((size_t)n * HID * 2));
    __half* hbuf   = (__half*)(ws + alloc((size_t)n * HID * 2));
    __half* W0T    = (__half*)(ws + alloc((size_t)NCLUST * 128 * 64 * 2));
    __half* WhT    = (__half*)(ws + alloc((size_t)2 * NCLUST * 128 * 128 * 2));
    float*  pool   = (float*)(ws + alloc((size_t)NLAYERS * NGRAPH * HID * 4));
    float*  z1     = (float*)(ws + alloc((size_t)NGRAPH * HID * 4));
    int* ccur = cc + 8;

    // setup: pool + cc + bcur + cvt + W transposes, one kernel
    long setup_items = (long)NLAYERS * NGRAPH * HID + 12 + NBMAX +
                       (long)n * IN / 4 + NCLUST * 128 * 64 + 2 * NCLUST * 128 * 128;
    int setup_blocks = (int)((setup_items + 255) / 256);
    hipLaunchKernelGGL(k_setup, dim3(setup_blocks), dim3(256), 0, stream,
                       x, x16, n * IN, W0, W0T, Wh, WhT, pool, cc, bcur);
    hipLaunchKernelGGL(k_bin, dim3((E + BIN_CHUNK - 1) / BIN_CHUNK), dim3(256), 0, stream,
                       ei, bcur, stage, E);
    hipLaunchKernelGGL(k_csrify, dim3(nbuck), dim3(512), 0, stream,
                       stage, bcur, esrc, offs, deg, dinv, cluster, ccur, clist, n);

    dim3 tgrid((n + 63) / 64, NCLUST);
    int aggblocks = (n + 3) / 4;

    // ---- layer 0 (K=64) ----
    hipLaunchKernelGGL(k_agg64, dim3(aggblocks), dim3(256), 0, stream,
                       x16, offs, deg, esrc, dinv, agg16, n);
    hipLaunchKernelGGL(k_tf<64>, tgrid, dim3(256), 0, stream,
                       agg16, W0T, b0, ccur, clist, batch,
                       pool + 0 * NGRAPH * HID, hbuf, n);

    // ---- layers 1..2 (K=128) ----
    for (int t = 1; t < NLAYERS; ++t) {
        hipLaunchKernelGGL(k_agg128, dim3(aggblocks), dim3(256), 0, stream,
                           hbuf, offs, deg, esrc, dinv, agg16, n);
        hipLaunchKernelGGL(k_tf<128>, tgrid, dim3(256), 0, stream,
                           agg16, WhT + (size_t)(t - 1) * NCLUST * 128 * 128,
                           bh + (size_t)(t - 1) * NCLUST * HID,
                           ccur, clist, batch, pool + (size_t)t * NGRAPH * HID, hbuf, n);
    }

    // ---- head ----
    hipLaunchKernelGGL(k_mlp1, dim3(NGRAPH), dim3(128), 0, stream, pool, W1, b1, z1);
    hipLaunchKernelGGL(k_mlp2, dim3(1), dim3(256), 0, stream, z1, gamma, beta, W2, b2, out);

    (void)n_in; (void)out_size; (void)ws_size;
}